// Round 7
// baseline (562.101 us; speedup 1.0000x reference)
//
#include <hip/hip_runtime.h>

// ---------------------------------------------------------------------------
// MultiHeadSelfAttention: x[4,2048,768] -> (out[4,2048,768], att[4,12,2048,2048])
// Pipeline: cvt/transpose -> QKV GEMM -> k_lsum (softmax denom) -> k_att -> proj
// ---------------------------------------------------------------------------

typedef __attribute__((ext_vector_type(8)))  short          bf16x8;   // 8 bf16 (4 VGPR)
typedef __attribute__((ext_vector_type(4)))  float          f32x4;
typedef __attribute__((ext_vector_type(16))) float          f32x16;
typedef __attribute__((ext_vector_type(4)))  unsigned short us4;
typedef __attribute__((ext_vector_type(4)))  int            i32x4;
typedef __attribute__((ext_vector_type(4)))  unsigned int   u32x4;
typedef __attribute__((ext_vector_type(2)))  unsigned int   u32x2;

#define DEVFN static __device__ __forceinline__

enum : int { Bb = 4, Nn = 2048, Cc = 768, Hh = 12, Dd = 64, BH = 48, Mm = 8192, C3 = 2304 };

DEVFN unsigned short f2bf(float f) {
    unsigned int u = __float_as_uint(f);
    u = (u + 0x7fffu + ((u >> 16) & 1u)) >> 16;   // RNE
    return (unsigned short)u;
}

DEVFN void gload16(void* lds, const void* g) {
    __builtin_amdgcn_global_load_lds(
        (__attribute__((address_space(1))) void*)(g),
        (__attribute__((address_space(3))) void*)(lds), 16, 0, 0);
}

DEVFN f32x4 mfma_bf16(bf16x8 a, bf16x8 b, f32x4 c) {
    return __builtin_amdgcn_mfma_f32_16x16x32_bf16(a, b, c, 0, 0, 0);
}
DEVFN f32x16 mfma32(bf16x8 a, bf16x8 b, f32x16 c) {
    return __builtin_amdgcn_mfma_f32_32x32x16_bf16(a, b, c, 0, 0, 0);
}
DEVFN unsigned cvt_pk_bf16(float lo, float hi) {
    unsigned r;
    asm("v_cvt_pk_bf16_f32 %0, %1, %2" : "=v"(r) : "v"(lo), "v"(hi));
    return r;
}

// ---------------------------------------------------------------- cvt x->bf16
__global__ __launch_bounds__(256) void k_cvt_bf16(const float* __restrict__ in,
                                                  unsigned short* __restrict__ out, int n4) {
    int i = blockIdx.x * 256 + threadIdx.x;
    if (i < n4) {
        f32x4 v = ((const f32x4*)in)[i];
        us4 o;
        o[0] = f2bf(v[0]); o[1] = f2bf(v[1]); o[2] = f2bf(v[2]); o[3] = f2bf(v[3]);
        ((us4*)out)[i] = o;
    }
}

// ------------------------------------------------- transpose f32[R][C] -> bf16[C][R]
__global__ __launch_bounds__(256) void k_transpose_bf16(const float* __restrict__ in,
                                                        unsigned short* __restrict__ out,
                                                        int R, int Ccols) {
    __shared__ float t[64][65];
    int r0 = blockIdx.x * 64, c0 = blockIdx.y * 64;
    int tid = threadIdx.x;
#pragma unroll
    for (int i = 0; i < 16; i++) {
        int idx = i * 256 + tid; int lr = idx >> 6, lc = idx & 63;
        t[lr][lc] = in[(size_t)(r0 + lr) * Ccols + c0 + lc];
    }
    __syncthreads();
#pragma unroll
    for (int i = 0; i < 16; i++) {
        int idx = i * 256 + tid; int lc = idx >> 6, lr = idx & 63;
        out[(size_t)(c0 + lc) * R + r0 + lr] = f2bf(t[lr][lc]);
    }
}

// ------------------------------------------------------------- QKV GEMM
__global__ __launch_bounds__(256) void k_gemm_qkv(const unsigned short* __restrict__ A,
                                                  const unsigned short* __restrict__ Bt,
                                                  const float* __restrict__ bias,
                                                  unsigned short* __restrict__ qO,
                                                  unsigned short* __restrict__ kO,
                                                  unsigned short* __restrict__ vT) {
    __shared__ __align__(16) unsigned short As[128 * 64];
    __shared__ __align__(16) unsigned short Bs[128 * 64];
    char* AsB = (char*)As; char* BsB = (char*)Bs;
    int tid = threadIdx.x, lane = tid & 63, w = tid >> 6;
    int l15 = lane & 15, g = lane >> 4;
    int m0 = blockIdx.x * 128, n0 = blockIdx.y * 128;
    int wr = w >> 1, wc = w & 1;
    f32x4 acc[4][4] = {};

    for (int ks = 0; ks < 768; ks += 64) {
        __syncthreads();
#pragma unroll
        for (int i = 0; i < 4; i++) {
            int chunk = i * 256 + tid;
            int row = chunk >> 3, c8 = chunk & 7;
            gload16(AsB + chunk * 16, A + (size_t)(m0 + row) * 768 + ks + c8 * 8);
            gload16(BsB + chunk * 16, Bt + (size_t)(n0 + row) * 768 + ks + c8 * 8);
        }
        __syncthreads();
#pragma unroll
        for (int j = 0; j < 2; j++) {
            bf16x8 af[4], bf[4];
#pragma unroll
            for (int mb = 0; mb < 4; mb++) {
                int m = wr * 64 + mb * 16 + l15;
                af[mb] = *(const bf16x8*)(AsB + m * 128 + j * 64 + g * 16);
            }
#pragma unroll
            for (int nb = 0; nb < 4; nb++) {
                int n = wc * 64 + nb * 16 + l15;
                bf[nb] = *(const bf16x8*)(BsB + n * 128 + j * 64 + g * 16);
            }
#pragma unroll
            for (int mb = 0; mb < 4; mb++)
#pragma unroll
                for (int nb = 0; nb < 4; nb++)
                    acc[mb][nb] = mfma_bf16(af[mb], bf[nb], acc[mb][nb]);
        }
    }

    int which = n0 / 768;
#pragma unroll
    for (int nb = 0; nb < 4; nb++) {
        int n_g = n0 + wc * 64 + nb * 16 + l15;
        float bs = bias[n_g];
        int h = (n_g - which * 768) >> 6, d = n_g & 63;
#pragma unroll
        for (int mb = 0; mb < 4; mb++) {
            f32x4 v = acc[mb][nb];
#pragma unroll
            for (int r = 0; r < 4; r++) {
                int m_g = m0 + wr * 64 + mb * 16 + g * 4 + r;
                int bI = m_g >> 11, tok = m_g & 2047;
                int bh = bI * 12 + h;
                float val = v[r] + bs;
                if (which == 0)
                    qO[(size_t)(bh * 2048 + tok) * 64 + d] = f2bf(val * 0.125f);
                else if (which == 1)
                    kO[(size_t)(bh * 2048 + tok) * 64 + d] = f2bf(val);
                else
                    vT[(size_t)(bh * 64 + d) * 2048 + tok] = f2bf(val);
            }
        }
    }
}

// ------------------------------------------------------------- softmax denom
// 3072 WGs (48 bh x 64 q-tiles, XCD-bijective) x 256 threads (4 waves x 512 k).
// Swapped 32x32x16 MFMA (lane = q). Writes rinv[bh*2048 + q] to ws.
__global__ __launch_bounds__(256, 4) void k_lsum(const unsigned short* __restrict__ qb,
                                                 const unsigned short* __restrict__ kbuf,
                                                 const int* __restrict__ mask,
                                                 float* __restrict__ rinv_g) {
    __shared__ float l_part[128];

    int tid = threadIdx.x, lane = tid & 63, w = tid >> 6;
    int l31 = lane & 31, hi = lane >> 5;
    int n = blockIdx.x;
    int xcd = n & 7, slot = n >> 3;
    int bh = xcd * 6 + (slot >> 6), qt = slot & 63;
    int b = bh / 12;
    int q0 = qt * 32;

    const unsigned short* kbase = kbuf + (size_t)bh * 2048 * 64;
    const int* mbase = mask + b * 2048 + hi * 4;

    bf16x8 qf0, qf1, qf2, qf3;
    {
        const unsigned short* qp = qb + (size_t)(bh * 2048 + q0 + l31) * 64 + hi * 8;
        qf0 = *(const bf16x8*)(qp);
        qf1 = *(const bf16x8*)(qp + 16);
        qf2 = *(const bf16x8*)(qp + 32);
        qf3 = *(const bf16x8*)(qp + 48);
    }
    const unsigned short* kp = kbase + (size_t)l31 * 64 + hi * 8;

    float lsum = 0.f;
#pragma unroll 2
    for (int t = 0; t < 16; t++) {
        int k0 = w * 512 + t * 32;
        const unsigned short* kpt = kp + (size_t)k0 * 64;
        bf16x8 kf0 = *(const bf16x8*)(kpt);
        bf16x8 kf1 = *(const bf16x8*)(kpt + 16);
        bf16x8 kf2 = *(const bf16x8*)(kpt + 32);
        bf16x8 kf3 = *(const bf16x8*)(kpt + 48);
        i32x4 m0 = *(const i32x4*)(mbase + k0);
        i32x4 m1 = *(const i32x4*)(mbase + k0 + 8);
        i32x4 m2 = *(const i32x4*)(mbase + k0 + 16);
        i32x4 m3 = *(const i32x4*)(mbase + k0 + 24);
        f32x16 s = {};
        s = mfma32(kf0, qf0, s);
        s = mfma32(kf1, qf1, s);
        s = mfma32(kf2, qf2, s);
        s = mfma32(kf3, qf3, s);
#pragma unroll
        for (int i = 0; i < 4; i++) lsum += m0[i] ? __expf(fminf(s[i], 75.f)) : 0.f;
#pragma unroll
        for (int i = 0; i < 4; i++) lsum += m1[i] ? __expf(fminf(s[4 + i], 75.f)) : 0.f;
#pragma unroll
        for (int i = 0; i < 4; i++) lsum += m2[i] ? __expf(fminf(s[8 + i], 75.f)) : 0.f;
#pragma unroll
        for (int i = 0; i < 4; i++) lsum += m3[i] ? __expf(fminf(s[12 + i], 75.f)) : 0.f;
    }
    lsum += __shfl_xor(lsum, 32, 64);
    if (hi == 0) l_part[w * 32 + l31] = lsum;
    __syncthreads();
    if (tid < 32)
        rinv_g[(size_t)bh * 2048 + q0 + tid] =
            1.0f / (l_part[tid] + l_part[32 + tid] + l_part[64 + tid] + l_part[96 + tid]);
}

// ------------------------------------------------------------- fused attention
// BARRIER-FREE, LDS-FREE. 3072 blocks x 64 threads (1 wave = 32 q-rows).
// XCD-bijective bh mapping; K+V per XCD L2-resident.
//
// Same loaded qf/kf registers feed the MFMA in BOTH operand orders:
//  swapped   s_sw = mfma(kf,qf): lane=q  -> per-lane P, cvt_pk+permlane PV (ctx^T)
//  unswapped s_un = mfma(qf,kf): lane=k  -> reg r = one q-row, 32 lanes consecutive k
//                                           = 128B fully-coalesced att stores from regs
// rinv precomputed by k_lsum. exp computed twice (cheap) to avoid all transposes.
__global__ __launch_bounds__(64, 3) void k_att(const unsigned short* __restrict__ qb,
                                               const unsigned short* __restrict__ kbuf,
                                               const unsigned short* __restrict__ vT,
                                               const int* __restrict__ mask,
                                               const float* __restrict__ rinv_g,
                                               float* __restrict__ attO,
                                               unsigned short* __restrict__ ctx) {
    int lane = threadIdx.x & 63;
    int l31 = lane & 31, hi = lane >> 5;
    int n = blockIdx.x;
    int xcd = n & 7, slot = n >> 3;
    int bh = xcd * 6 + (slot >> 6), qt = slot & 63;
    int b = bh / 12, h = bh - b * 12;
    int q0 = qt * 32;

    const unsigned short* kbase = kbuf + (size_t)bh * 2048 * 64;
    const unsigned short* vbase = vT + (size_t)bh * 64 * 2048;
    const int* mrow = mask + b * 2048;
    const int* mbase = mrow + hi * 4;

    bf16x8 qf0, qf1, qf2, qf3;
    {
        const unsigned short* qp = qb + (size_t)(bh * 2048 + q0 + l31) * 64 + hi * 8;
        qf0 = *(const bf16x8*)(qp);
        qf1 = *(const bf16x8*)(qp + 16);
        qf2 = *(const bf16x8*)(qp + 32);
        qf3 = *(const bf16x8*)(qp + 48);
    }
    const unsigned short* kp = kbase + (size_t)l31 * 64 + hi * 8;
    const unsigned short* vp = vbase + (size_t)l31 * 2048 + hi * 8;

    // rinv: lane's own q (swapped path) + per-reg rows (unswapped path)
    float rinv_l = rinv_g[(size_t)bh * 2048 + q0 + l31];
    float rv[16];
#pragma unroll
    for (int r = 0; r < 16; r++)
        rv[r] = __shfl(rinv_l, (r & 3) + 8 * (r >> 2) + 4 * hi, 32);

    // att base for unswapped stores: row = q0 + (r&3)+8*(r>>2)+4*hi, col = kb + l31
    float* attq = attO + ((size_t)(bh * 2048 + q0 + 4 * hi)) * 2048 + l31;

    f32x16 c0 = {}, c1 = {};
    for (int kb = 0; kb < 2048; kb += 32) {
        const unsigned short* kpt = kp + (size_t)kb * 64;
        bf16x8 kf0 = *(const bf16x8*)(kpt);
        bf16x8 kf1 = *(const bf16x8*)(kpt + 16);
        bf16x8 kf2 = *(const bf16x8*)(kpt + 32);
        bf16x8 kf3 = *(const bf16x8*)(kpt + 48);
        bf16x8 vf00 = *(const bf16x8*)(vp + kb);
        bf16x8 vf01 = *(const bf16x8*)(vp + kb + 16);
        bf16x8 vf10 = *(const bf16x8*)(vp + 65536 + kb);
        bf16x8 vf11 = *(const bf16x8*)(vp + 65536 + kb + 16);
        int mk = mrow[kb + l31];                       // unswapped mask (lane = k)
        i32x4 m0 = *(const i32x4*)(mbase + kb);        // swapped masks (regs = k)
        i32x4 m1 = *(const i32x4*)(mbase + kb + 8);
        i32x4 m2 = *(const i32x4*)(mbase + kb + 16);
        i32x4 m3 = *(const i32x4*)(mbase + kb + 24);

        // ---- unswapped: S[q][k], lane = k; direct coalesced att stores ----
        {
            f32x16 su = {};
            su = mfma32(qf0, kf0, su);
            su = mfma32(qf1, kf1, su);
            su = mfma32(qf2, kf2, su);
            su = mfma32(qf3, kf3, su);
            float* ap = attq + kb;
#pragma unroll
            for (int r = 0; r < 16; r++) {
                float e = mk ? __expf(fminf(su[r], 75.f)) : 0.f;
                ap[((r & 3) + 8 * (r >> 2)) * 2048] = e * rv[r];
            }
        }

        // ---- swapped: S^T[k][q], lane = q; PV via cvt_pk + permlane ----
        {
            f32x16 s = {};
            s = mfma32(kf0, qf0, s);
            s = mfma32(kf1, qf1, s);
            s = mfma32(kf2, qf2, s);
            s = mfma32(kf3, qf3, s);
            unsigned pk00, pk01, pk10, pk11, pk20, pk21, pk30, pk31;
            {
                float a0 = (m0[0] ? __expf(fminf(s[0], 75.f)) : 0.f) * rinv_l;
                float a1 = (m0[1] ? __expf(fminf(s[1], 75.f)) : 0.f) * rinv_l;
                float a2 = (m0[2] ? __expf(fminf(s[2], 75.f)) : 0.f) * rinv_l;
                float a3 = (m0[3] ? __expf(fminf(s[3], 75.f)) : 0.f) * rinv_l;
                pk00 = cvt_pk_bf16(a0, a1); pk01 = cvt_pk_bf16(a2, a3);
            }
            {
                float a0 = (m1[0] ? __expf(fminf(s[4], 75.f)) : 0.f) * rinv_l;
                float a1 = (m1[1] ? __expf(fminf(s[5], 75.f)) : 0.f) * rinv_l;
                float a2 = (m1[2] ? __expf(fminf(s[6], 75.f)) : 0.f) * rinv_l;
                float a3 = (m1[3] ? __expf(fminf(s[7], 75.f)) : 0.f) * rinv_l;
                pk10 = cvt_pk_bf16(a0, a1); pk11 = cvt_pk_bf16(a2, a3);
            }
            {
                float a0 = (m2[0] ? __expf(fminf(s[8], 75.f)) : 0.f) * rinv_l;
                float a1 = (m2[1] ? __expf(fminf(s[9], 75.f)) : 0.f) * rinv_l;
                float a2 = (m2[2] ? __expf(fminf(s[10], 75.f)) : 0.f) * rinv_l;
                float a3 = (m2[3] ? __expf(fminf(s[11], 75.f)) : 0.f) * rinv_l;
                pk20 = cvt_pk_bf16(a0, a1); pk21 = cvt_pk_bf16(a2, a3);
            }
            {
                float a0 = (m3[0] ? __expf(fminf(s[12], 75.f)) : 0.f) * rinv_l;
                float a1 = (m3[1] ? __expf(fminf(s[13], 75.f)) : 0.f) * rinv_l;
                float a2 = (m3[2] ? __expf(fminf(s[14], 75.f)) : 0.f) * rinv_l;
                float a3 = (m3[3] ? __expf(fminf(s[15], 75.f)) : 0.f) * rinv_l;
                pk30 = cvt_pk_bf16(a0, a1); pk31 = cvt_pk_bf16(a2, a3);
            }
            {
                u32x2 sA = __builtin_amdgcn_permlane32_swap(pk00, pk10, false, false);
                u32x2 sB = __builtin_amdgcn_permlane32_swap(pk01, pk11, false, false);
                u32x4 bi = {sA[0], sB[0], sA[1], sB[1]};
                bf16x8 pf = __builtin_bit_cast(bf16x8, bi);
                c0 = mfma32(vf00, pf, c0);
                c1 = mfma32(vf10, pf, c1);
            }
            {
                u32x2 sA = __builtin_amdgcn_permlane32_swap(pk20, pk30, false, false);
                u32x2 sB = __builtin_amdgcn_permlane32_swap(pk21, pk31, false, false);
                u32x4 bi = {sA[0], sB[0], sA[1], sB[1]};
                bf16x8 pf = __builtin_bit_cast(bf16x8, bi);
                c0 = mfma32(vf01, pf, c0);
                c1 = mfma32(vf11, pf, c1);
            }
        }
    }
    // ctx^T store: lane l31 = q; c0 d = (r&3)+8*(r>>2)+4*hi, c1 d+32.
    {
        unsigned short* cp = ctx + (size_t)(b * 2048 + q0 + l31) * 768 + h * 64 + hi * 4;
#pragma unroll
        for (int j = 0; j < 4; j++) {
            us4 o0, o1;
            o0[0] = f2bf(c0[4 * j + 0]); o0[1] = f2bf(c0[4 * j + 1]);
            o0[2] = f2bf(c0[4 * j + 2]); o0[3] = f2bf(c0[4 * j + 3]);
            o1[0] = f2bf(c1[4 * j + 0]); o1[1] = f2bf(c1[4 * j + 1]);
            o1[2] = f2bf(c1[4 * j + 2]); o1[3] = f2bf(c1[4 * j + 3]);
            *(us4*)(cp + 8 * j) = o0;
            *(us4*)(cp + 32 + 8 * j) = o1;
        }
    }
}

// ------------------------------------------------------------- proj GEMM
__global__ __launch_bounds__(256) void k_gemm_proj(const unsigned short* __restrict__ A,
                                                   const unsigned short* __restrict__ Bt,
                                                   const float* __restrict__ bias,
                                                   float* __restrict__ out) {
    __shared__ __align__(16) unsigned short As[128 * 64];
    __shared__ __align__(16) unsigned short Bs[128 * 64];
    char* AsB = (char*)As; char* BsB = (char*)Bs;
    int tid = threadIdx.x, lane = tid & 63, w = tid >> 6;
    int l15 = lane & 15, g = lane >> 4;
    int m0 = blockIdx.x * 128, n0 = blockIdx.y * 128;
    int wr = w >> 1, wc = w & 1;
    f32x4 acc[4][4] = {};

    for (int ks = 0; ks < 768; ks += 64) {
        __syncthreads();
#pragma unroll
        for (int i = 0; i < 4; i++) {
            int chunk = i * 256 + tid;
            int row = chunk >> 3, c8 = chunk & 7;
            gload16(AsB + chunk * 16, A + (size_t)(m0 + row) * 768 + ks + c8 * 8);
            gload16(BsB + chunk * 16, Bt + (size_t)(n0 + row) * 768 + ks + c8 * 8);
        }
        __syncthreads();
#pragma unroll
        for (int j = 0; j < 2; j++) {
            bf16x8 af[4], bf[4];
#pragma unroll
            for (int mb = 0; mb < 4; mb++) {
                int m = wr * 64 + mb * 16 + l15;
                af[mb] = *(const bf16x8*)(AsB + m * 128 + j * 64 + g * 16);
            }
#pragma unroll
            for (int nb = 0; nb < 4; nb++) {
                int n = wc * 64 + nb * 16 + l15;
                bf[nb] = *(const bf16x8*)(BsB + n * 128 + j * 64 + g * 16);
            }
#pragma unroll
            for (int mb = 0; mb < 4; mb++)
#pragma unroll
                for (int nb = 0; nb < 4; nb++)
                    acc[mb][nb] = mfma_bf16(af[mb], bf[nb], acc[mb][nb]);
        }
    }
#pragma unroll
    for (int nb = 0; nb < 4; nb++) {
        int n_g = n0 + wc * 64 + nb * 16 + l15;
        float bs = bias[n_g];
#pragma unroll
        for (int mb = 0; mb < 4; mb++) {
            f32x4 v = acc[mb][nb];
#pragma unroll
            for (int r = 0; r < 4; r++) {
                int m_g = m0 + wr * 64 + mb * 16 + g * 4 + r;
                out[(size_t)m_g * 768 + n_g] = v[r] + bs;
            }
        }
    }
}

// ---------------------------------------------------------------------------
extern "C" void kernel_launch(void* const* d_in, const int* in_sizes, int n_in,
                              void* d_out, int out_size, void* d_ws, size_t ws_size,
                              hipStream_t stream) {
    (void)in_sizes; (void)n_in; (void)out_size; (void)ws_size;
    const float* x      = (const float*)d_in[0];
    const int*   mask   = (const int*)d_in[1];
    const float* w_qkv  = (const float*)d_in[2];
    const float* b_qkv  = (const float*)d_in[3];
    const float* w_proj = (const float*)d_in[4];
    const float* b_proj = (const float*)d_in[5];
    const float* pb     = (const float*)d_in[6];
    (void)pb;

    float* out  = (float*)d_out;
    float* attO = out + (size_t)Bb * Nn * Cc;   // 6,291,456

    char* ws = (char*)d_ws;
    unsigned short* xb     = (unsigned short*)(ws);             // 12,582,912 B
    unsigned short* wqkvt  = (unsigned short*)(ws + 12582912);  //  3,538,944 B
    unsigned short* wprojt = (unsigned short*)(ws + 16121856);  //  1,179,648 B
    unsigned short* qbuf   = (unsigned short*)(ws + 17301504);  // 12,582,912 B
    unsigned short* kbuf   = (unsigned short*)(ws + 29884416);  // 12,582,912 B
    unsigned short* vtb    = (unsigned short*)(ws + 42467328);  // 12,582,912 B
    unsigned short* ctx    = (unsigned short*)(ws + 55050240);  // 12,582,912 B
    float*          rinv   = (float*)(ws + 67633152);           //    393,216 B (total ~68.0 MB)

    k_cvt_bf16<<<6144, 256, 0, stream>>>(x, xb, 1572864);
    k_transpose_bf16<<<dim3(12, 36), 256, 0, stream>>>(w_qkv, wqkvt, 768, 2304);
    k_transpose_bf16<<<dim3(12, 12), 256, 0, stream>>>(w_proj, wprojt, 768, 768);
    k_gemm_qkv<<<dim3(64, 18), 256, 0, stream>>>(xb, wqkvt, b_qkv, qbuf, kbuf, vtb);
    k_lsum<<<3072, 256, 0, stream>>>(qbuf, kbuf, mask, rinv);
    k_att<<<3072, 64, 0, stream>>>(qbuf, kbuf, vtb, mask, rinv, attO, ctx);
    k_gemm_proj<<<dim3(64, 6), 256, 0, stream>>>(ctx, wprojt, b_proj, out);
}

// Round 8
// 457.405 us; speedup vs baseline: 1.2289x; 1.2289x over previous
//
#include <hip/hip_runtime.h>

// ---------------------------------------------------------------------------
// MultiHeadSelfAttention: x[4,2048,768] -> (out[4,2048,768], att[4,12,2048,2048])
// Pipeline: cvt/transpose -> QKV GEMM (bf16 MFMA) -> fused attention -> proj GEMM
// R8 = R6 + nontemporal att write-back (full-line bursts; L2-bypass test, H2)
// ---------------------------------------------------------------------------

typedef __attribute__((ext_vector_type(8)))  short          bf16x8;   // 8 bf16 (4 VGPR)
typedef __attribute__((ext_vector_type(4)))  float          f32x4;
typedef __attribute__((ext_vector_type(16))) float          f32x16;
typedef __attribute__((ext_vector_type(4)))  unsigned short us4;
typedef __attribute__((ext_vector_type(4)))  int            i32x4;
typedef __attribute__((ext_vector_type(4)))  unsigned int   u32x4;
typedef __attribute__((ext_vector_type(2)))  unsigned int   u32x2;

#define DEVFN static __device__ __forceinline__

enum : int { Bb = 4, Nn = 2048, Cc = 768, Hh = 12, Dd = 64, BH = 48, Mm = 8192, C3 = 2304 };

DEVFN unsigned short f2bf(float f) {
    unsigned int u = __float_as_uint(f);
    u = (u + 0x7fffu + ((u >> 16) & 1u)) >> 16;   // RNE
    return (unsigned short)u;
}

DEVFN void gload16(void* lds, const void* g) {
    __builtin_amdgcn_global_load_lds(
        (__attribute__((address_space(1))) void*)(g),
        (__attribute__((address_space(3))) void*)(lds), 16, 0, 0);
}

DEVFN f32x4 mfma_bf16(bf16x8 a, bf16x8 b, f32x4 c) {
    return __builtin_amdgcn_mfma_f32_16x16x32_bf16(a, b, c, 0, 0, 0);
}
DEVFN f32x16 mfma32(bf16x8 a, bf16x8 b, f32x16 c) {
    return __builtin_amdgcn_mfma_f32_32x32x16_bf16(a, b, c, 0, 0, 0);
}
DEVFN unsigned cvt_pk_bf16(float lo, float hi) {
    unsigned r;
    asm("v_cvt_pk_bf16_f32 %0, %1, %2" : "=v"(r) : "v"(lo), "v"(hi));
    return r;
}

// ---------------------------------------------------------------- cvt x->bf16
__global__ __launch_bounds__(256) void k_cvt_bf16(const float* __restrict__ in,
                                                  unsigned short* __restrict__ out, int n4) {
    int i = blockIdx.x * 256 + threadIdx.x;
    if (i < n4) {
        f32x4 v = ((const f32x4*)in)[i];
        us4 o;
        o[0] = f2bf(v[0]); o[1] = f2bf(v[1]); o[2] = f2bf(v[2]); o[3] = f2bf(v[3]);
        ((us4*)out)[i] = o;
    }
}

// ------------------------------------------------- transpose f32[R][C] -> bf16[C][R]
__global__ __launch_bounds__(256) void k_transpose_bf16(const float* __restrict__ in,
                                                        unsigned short* __restrict__ out,
                                                        int R, int Ccols) {
    __shared__ float t[64][65];
    int r0 = blockIdx.x * 64, c0 = blockIdx.y * 64;
    int tid = threadIdx.x;
#pragma unroll
    for (int i = 0; i < 16; i++) {
        int idx = i * 256 + tid; int lr = idx >> 6, lc = idx & 63;
        t[lr][lc] = in[(size_t)(r0 + lr) * Ccols + c0 + lc];
    }
    __syncthreads();
#pragma unroll
    for (int i = 0; i < 16; i++) {
        int idx = i * 256 + tid; int lc = idx >> 6, lr = idx & 63;
        out[(size_t)(c0 + lc) * R + r0 + lr] = f2bf(t[lr][lc]);
    }
}

// ------------------------------------------------------------- QKV GEMM
__global__ __launch_bounds__(256) void k_gemm_qkv(const unsigned short* __restrict__ A,
                                                  const unsigned short* __restrict__ Bt,
                                                  const float* __restrict__ bias,
                                                  unsigned short* __restrict__ qO,
                                                  unsigned short* __restrict__ kO,
                                                  unsigned short* __restrict__ vT) {
    __shared__ __align__(16) unsigned short As[128 * 64];
    __shared__ __align__(16) unsigned short Bs[128 * 64];
    char* AsB = (char*)As; char* BsB = (char*)Bs;
    int tid = threadIdx.x, lane = tid & 63, w = tid >> 6;
    int l15 = lane & 15, g = lane >> 4;
    int m0 = blockIdx.x * 128, n0 = blockIdx.y * 128;
    int wr = w >> 1, wc = w & 1;
    f32x4 acc[4][4] = {};

    for (int ks = 0; ks < 768; ks += 64) {
        __syncthreads();
#pragma unroll
        for (int i = 0; i < 4; i++) {
            int chunk = i * 256 + tid;
            int row = chunk >> 3, c8 = chunk & 7;
            gload16(AsB + chunk * 16, A + (size_t)(m0 + row) * 768 + ks + c8 * 8);
            gload16(BsB + chunk * 16, Bt + (size_t)(n0 + row) * 768 + ks + c8 * 8);
        }
        __syncthreads();
#pragma unroll
        for (int j = 0; j < 2; j++) {
            bf16x8 af[4], bf[4];
#pragma unroll
            for (int mb = 0; mb < 4; mb++) {
                int m = wr * 64 + mb * 16 + l15;
                af[mb] = *(const bf16x8*)(AsB + m * 128 + j * 64 + g * 16);
            }
#pragma unroll
            for (int nb = 0; nb < 4; nb++) {
                int n = wc * 64 + nb * 16 + l15;
                bf[nb] = *(const bf16x8*)(BsB + n * 128 + j * 64 + g * 16);
            }
#pragma unroll
            for (int mb = 0; mb < 4; mb++)
#pragma unroll
                for (int nb = 0; nb < 4; nb++)
                    acc[mb][nb] = mfma_bf16(af[mb], bf[nb], acc[mb][nb]);
        }
    }

    int which = n0 / 768;
#pragma unroll
    for (int nb = 0; nb < 4; nb++) {
        int n_g = n0 + wc * 64 + nb * 16 + l15;
        float bs = bias[n_g];
        int h = (n_g - which * 768) >> 6, d = n_g & 63;
#pragma unroll
        for (int mb = 0; mb < 4; mb++) {
            f32x4 v = acc[mb][nb];
#pragma unroll
            for (int r = 0; r < 4; r++) {
                int m_g = m0 + wr * 64 + mb * 16 + g * 4 + r;
                int bI = m_g >> 11, tok = m_g & 2047;
                int bh = bI * 12 + h;
                float val = v[r] + bs;
                if (which == 0)
                    qO[(size_t)(bh * 2048 + tok) * 64 + d] = f2bf(val * 0.125f);
                else if (which == 1)
                    kO[(size_t)(bh * 2048 + tok) * 64 + d] = f2bf(val);
                else
                    vT[(size_t)(bh * 64 + d) * 2048 + tok] = f2bf(val);
            }
        }
    }
}

// ------------------------------------------------------------- fused attention
// 3072 WGs (48 bh x 64 q-tiles, XCD-bijective) x 256 threads (4 waves).
// Identical to R6 except: att write-back uses nontemporal full-line stores
// (L2-bypass) to stop the 805MB att stream from evicting the K/V working set.
__global__ __launch_bounds__(256, 4) void k_attn(const unsigned short* __restrict__ qb,
                                                 const unsigned short* __restrict__ kbuf,
                                                 const unsigned short* __restrict__ vT,
                                                 const int* __restrict__ mask,
                                                 const float* __restrict__ pbias,
                                                 float* __restrict__ attO,
                                                 unsigned short* __restrict__ ctx) {
    // Ssm [32][261] f32 = 33408 B; ctx overlay [4][32][65] f32 = 33280 B (fits).
    __shared__ __align__(16) char smem[33408 + 512 + 128];
    float* Ssm    = (float*)smem;
    float* l_part = (float*)(smem + 33408);   // [4][32]
    float* rowinv = (float*)(smem + 33920);   // [32]

    int tid = threadIdx.x, lane = tid & 63, w = tid >> 6;   // w = 0..3
    int l31 = lane & 31, hi = lane >> 5;
    int n = blockIdx.x;
    int xcd = n & 7, slot = n >> 3;
    int bh = xcd * 6 + (slot >> 6), qt = slot & 63;
    int b = bh / 12, h = bh - b * 12;
    int q0 = qt * 32;
    (void)pbias;

    const unsigned short* kbase = kbuf + (size_t)bh * 2048 * 64;
    const unsigned short* vbase = vT + (size_t)bh * 64 * 2048;
    const int* mbase = mask + b * 2048 + hi * 4;

    // Q^T B-frags for q = q0 + l31 (0.125 pre-folded)
    bf16x8 qf0, qf1, qf2, qf3;
    {
        const unsigned short* qp = qb + (size_t)(bh * 2048 + q0 + l31) * 64 + hi * 8;
        qf0 = *(const bf16x8*)(qp);
        qf1 = *(const bf16x8*)(qp + 16);
        qf2 = *(const bf16x8*)(qp + 32);
        qf3 = *(const bf16x8*)(qp + 48);
    }
    const unsigned short* kp = kbase + (size_t)l31 * 64 + hi * 8;
    const unsigned short* vp = vbase + (size_t)l31 * 2048 + hi * 8;

    // ---------------- Phase A: lsum over wave's k-slice [w*512, w*512+512) ----------------
    float lsum = 0.f;
#pragma unroll 2
    for (int t = 0; t < 16; t++) {
        int k0 = w * 512 + t * 32;
        const unsigned short* kpt = kp + (size_t)k0 * 64;
        bf16x8 kf0 = *(const bf16x8*)(kpt);
        bf16x8 kf1 = *(const bf16x8*)(kpt + 16);
        bf16x8 kf2 = *(const bf16x8*)(kpt + 32);
        bf16x8 kf3 = *(const bf16x8*)(kpt + 48);
        i32x4 m0 = *(const i32x4*)(mbase + k0);
        i32x4 m1 = *(const i32x4*)(mbase + k0 + 8);
        i32x4 m2 = *(const i32x4*)(mbase + k0 + 16);
        i32x4 m3 = *(const i32x4*)(mbase + k0 + 24);
        f32x16 s = {};
        s = mfma32(kf0, qf0, s);
        s = mfma32(kf1, qf1, s);
        s = mfma32(kf2, qf2, s);
        s = mfma32(kf3, qf3, s);
#pragma unroll
        for (int i = 0; i < 4; i++) lsum += m0[i] ? __expf(fminf(s[i], 75.f)) : 0.f;
#pragma unroll
        for (int i = 0; i < 4; i++) lsum += m1[i] ? __expf(fminf(s[4 + i], 75.f)) : 0.f;
#pragma unroll
        for (int i = 0; i < 4; i++) lsum += m2[i] ? __expf(fminf(s[8 + i], 75.f)) : 0.f;
#pragma unroll
        for (int i = 0; i < 4; i++) lsum += m3[i] ? __expf(fminf(s[12 + i], 75.f)) : 0.f;
    }
    lsum += __shfl_xor(lsum, 32, 64);
    if (hi == 0) l_part[w * 32 + l31] = lsum;
    __syncthreads();
    if (tid < 32)
        rowinv[tid] = 1.0f / (l_part[tid] + l_part[32 + tid] + l_part[64 + tid] + l_part[96 + tid]);
    __syncthreads();
    float rinv = rowinv[l31];

    // ---------------- Phase B: 8 phases of 256 k ----------------
    f32x16 c0 = {}, c1 = {};
    for (int p = 0; p < 8; p++) {
#pragma unroll
        for (int t = 0; t < 2; t++) {
            int kq0 = w * 64 + t * 32;            // col within phase tile
            int k0 = p * 256 + kq0;               // global k
            const unsigned short* kpt = kp + (size_t)k0 * 64;
            bf16x8 kf0 = *(const bf16x8*)(kpt);
            bf16x8 kf1 = *(const bf16x8*)(kpt + 16);
            bf16x8 kf2 = *(const bf16x8*)(kpt + 32);
            bf16x8 kf3 = *(const bf16x8*)(kpt + 48);
            bf16x8 vf00 = *(const bf16x8*)(vp + k0);
            bf16x8 vf01 = *(const bf16x8*)(vp + k0 + 16);
            bf16x8 vf10 = *(const bf16x8*)(vp + 65536 + k0);
            bf16x8 vf11 = *(const bf16x8*)(vp + 65536 + k0 + 16);
            i32x4 m0 = *(const i32x4*)(mbase + k0);
            i32x4 m1 = *(const i32x4*)(mbase + k0 + 8);
            i32x4 m2 = *(const i32x4*)(mbase + k0 + 16);
            i32x4 m3 = *(const i32x4*)(mbase + k0 + 24);
            f32x16 s = {};
            s = mfma32(kf0, qf0, s);
            s = mfma32(kf1, qf1, s);
            s = mfma32(kf2, qf2, s);
            s = mfma32(kf3, qf3, s);

            float* srow = Ssm + l31 * 261 + kq0 + 4 * hi;
            unsigned pk00, pk01, pk10, pk11, pk20, pk21, pk30, pk31;
            {
                float a0 = (m0[0] ? __expf(fminf(s[0], 75.f)) : 0.f) * rinv;
                float a1 = (m0[1] ? __expf(fminf(s[1], 75.f)) : 0.f) * rinv;
                float a2 = (m0[2] ? __expf(fminf(s[2], 75.f)) : 0.f) * rinv;
                float a3 = (m0[3] ? __expf(fminf(s[3], 75.f)) : 0.f) * rinv;
                f32x4 av = {a0, a1, a2, a3};
                *(f32x4*)(srow) = av;
                pk00 = cvt_pk_bf16(a0, a1); pk01 = cvt_pk_bf16(a2, a3);
            }
            {
                float a0 = (m1[0] ? __expf(fminf(s[4], 75.f)) : 0.f) * rinv;
                float a1 = (m1[1] ? __expf(fminf(s[5], 75.f)) : 0.f) * rinv;
                float a2 = (m1[2] ? __expf(fminf(s[6], 75.f)) : 0.f) * rinv;
                float a3 = (m1[3] ? __expf(fminf(s[7], 75.f)) : 0.f) * rinv;
                f32x4 av = {a0, a1, a2, a3};
                *(f32x4*)(srow + 8) = av;
                pk10 = cvt_pk_bf16(a0, a1); pk11 = cvt_pk_bf16(a2, a3);
            }
            {
                float a0 = (m2[0] ? __expf(fminf(s[8], 75.f)) : 0.f) * rinv;
                float a1 = (m2[1] ? __expf(fminf(s[9], 75.f)) : 0.f) * rinv;
                float a2 = (m2[2] ? __expf(fminf(s[10], 75.f)) : 0.f) * rinv;
                float a3 = (m2[3] ? __expf(fminf(s[11], 75.f)) : 0.f) * rinv;
                f32x4 av = {a0, a1, a2, a3};
                *(f32x4*)(srow + 16) = av;
                pk20 = cvt_pk_bf16(a0, a1); pk21 = cvt_pk_bf16(a2, a3);
            }
            {
                float a0 = (m3[0] ? __expf(fminf(s[12], 75.f)) : 0.f) * rinv;
                float a1 = (m3[1] ? __expf(fminf(s[13], 75.f)) : 0.f) * rinv;
                float a2 = (m3[2] ? __expf(fminf(s[14], 75.f)) : 0.f) * rinv;
                float a3 = (m3[3] ? __expf(fminf(s[15], 75.f)) : 0.f) * rinv;
                f32x4 av = {a0, a1, a2, a3};
                *(f32x4*)(srow + 24) = av;
                pk30 = cvt_pk_bf16(a0, a1); pk31 = cvt_pk_bf16(a2, a3);
            }
            {
                u32x2 sA = __builtin_amdgcn_permlane32_swap(pk00, pk10, false, false);
                u32x2 sB = __builtin_amdgcn_permlane32_swap(pk01, pk11, false, false);
                u32x4 bi = {sA[0], sB[0], sA[1], sB[1]};
                bf16x8 pf = __builtin_bit_cast(bf16x8, bi);
                c0 = mfma32(vf00, pf, c0);
                c1 = mfma32(vf10, pf, c1);
            }
            {
                u32x2 sA = __builtin_amdgcn_permlane32_swap(pk20, pk30, false, false);
                u32x2 sB = __builtin_amdgcn_permlane32_swap(pk21, pk31, false, false);
                u32x4 bi = {sA[0], sB[0], sA[1], sB[1]};
                bf16x8 pf = __builtin_bit_cast(bf16x8, bi);
                c0 = mfma32(vf01, pf, c0);
                c1 = mfma32(vf11, pf, c1);
            }
        }
        __syncthreads();
        // write-back: wave w streams rows 8w..8w+7; NONTEMPORAL full-line bursts
        {
            int c16 = lane & 15;
#pragma unroll
            for (int jj = 0; jj < 2; jj++) {
                int row = 8 * w + 4 * jj + (lane >> 4);
                const float* src = Ssm + row * 261 + c16 * 4;
                float* dst = attO + ((size_t)(bh * 2048 + q0 + row)) * 2048 + p * 256 + c16 * 4;
#pragma unroll
                for (int j = 0; j < 4; j++)
                    __builtin_nontemporal_store(*(const f32x4*)(src + j * 64),
                                                (f32x4*)(dst + j * 64));
            }
        }
        __syncthreads();
    }

    // ---------------- ctx: two-step wave-partial reduction ----------------
    {
        float* cw = Ssm + w * 2080 + l31 * 65;   // [4][32][65] overlay
#pragma unroll
        for (int r = 0; r < 16; r++) {
            int d = (r & 3) + 8 * (r >> 2) + 4 * hi;
            cw[d] = c0[r];
            cw[d + 32] = c1[r];
        }
    }
    __syncthreads();
    {
        int q = tid >> 3, d0 = (tid & 7) * 8;
        float a[8];
#pragma unroll
        for (int j = 0; j < 8; j++) a[j] = 0.f;
#pragma unroll
        for (int w2 = 0; w2 < 4; w2++) {
            const float* cw = Ssm + w2 * 2080 + q * 65 + d0;
#pragma unroll
            for (int j = 0; j < 8; j++) a[j] += cw[j];
        }
        us4 o0, o1;
        o0[0] = f2bf(a[0]); o0[1] = f2bf(a[1]); o0[2] = f2bf(a[2]); o0[3] = f2bf(a[3]);
        o1[0] = f2bf(a[4]); o1[1] = f2bf(a[5]); o1[2] = f2bf(a[6]); o1[3] = f2bf(a[7]);
        unsigned short* cp = ctx + (size_t)(b * 2048 + q0 + q) * 768 + h * 64 + d0;
        *(us4*)(cp) = o0;
        *(us4*)(cp + 4) = o1;
    }
}

// ------------------------------------------------------------- proj GEMM
__global__ __launch_bounds__(256) void k_gemm_proj(const unsigned short* __restrict__ A,
                                                   const unsigned short* __restrict__ Bt,
                                                   const float* __restrict__ bias,
                                                   float* __restrict__ out) {
    __shared__ __align__(16) unsigned short As[128 * 64];
    __shared__ __align__(16) unsigned short Bs[128 * 64];
    char* AsB = (char*)As; char* BsB = (char*)Bs;
    int tid = threadIdx.x, lane = tid & 63, w = tid >> 6;
    int l15 = lane & 15, g = lane >> 4;
    int m0 = blockIdx.x * 128, n0 = blockIdx.y * 128;
    int wr = w >> 1, wc = w & 1;
    f32x4 acc[4][4] = {};

    for (int ks = 0; ks < 768; ks += 64) {
        __syncthreads();
#pragma unroll
        for (int i = 0; i < 4; i++) {
            int chunk = i * 256 + tid;
            int row = chunk >> 3, c8 = chunk & 7;
            gload16(AsB + chunk * 16, A + (size_t)(m0 + row) * 768 + ks + c8 * 8);
            gload16(BsB + chunk * 16, Bt + (size_t)(n0 + row) * 768 + ks + c8 * 8);
        }
        __syncthreads();
#pragma unroll
        for (int j = 0; j < 2; j++) {
            bf16x8 af[4], bf[4];
#pragma unroll
            for (int mb = 0; mb < 4; mb++) {
                int m = wr * 64 + mb * 16 + l15;
                af[mb] = *(const bf16x8*)(AsB + m * 128 + j * 64 + g * 16);
            }
#pragma unroll
            for (int nb = 0; nb < 4; nb++) {
                int n = wc * 64 + nb * 16 + l15;
                bf[nb] = *(const bf16x8*)(BsB + n * 128 + j * 64 + g * 16);
            }
#pragma unroll
            for (int mb = 0; mb < 4; mb++)
#pragma unroll
                for (int nb = 0; nb < 4; nb++)
                    acc[mb][nb] = mfma_bf16(af[mb], bf[nb], acc[mb][nb]);
        }
    }
#pragma unroll
    for (int nb = 0; nb < 4; nb++) {
        int n_g = n0 + wc * 64 + nb * 16 + l15;
        float bs = bias[n_g];
#pragma unroll
        for (int mb = 0; mb < 4; mb++) {
            f32x4 v = acc[mb][nb];
#pragma unroll
            for (int r = 0; r < 4; r++) {
                int m_g = m0 + wr * 64 + mb * 16 + g * 4 + r;
                out[(size_t)m_g * 768 + n_g] = v[r] + bs;
            }
        }
    }
}

// ---------------------------------------------------------------------------
extern "C" void kernel_launch(void* const* d_in, const int* in_sizes, int n_in,
                              void* d_out, int out_size, void* d_ws, size_t ws_size,
                              hipStream_t stream) {
    (void)in_sizes; (void)n_in; (void)out_size; (void)ws_size;
    const float* x      = (const float*)d_in[0];
    const int*   mask   = (const int*)d_in[1];
    const float* w_qkv  = (const float*)d_in[2];
    const float* b_qkv  = (const float*)d_in[3];
    const float* w_proj = (const float*)d_in[4];
    const float* b_proj = (const float*)d_in[5];
    const float* pb     = (const float*)d_in[6];
    (void)pb;

    float* out  = (float*)d_out;
    float* attO = out + (size_t)Bb * Nn * Cc;   // 6,291,456

    char* ws = (char*)d_ws;
    unsigned short* xb     = (unsigned short*)(ws);             // 12,582,912 B
    unsigned short* wqkvt  = (unsigned short*)(ws + 12582912);  //  3,538,944 B
    unsigned short* wprojt = (unsigned short*)(ws + 16121856);  //  1,179,648 B
    unsigned short* qbuf   = (unsigned short*)(ws + 17301504);  // 12,582,912 B
    unsigned short* kbuf   = (unsigned short*)(ws + 29884416);  // 12,582,912 B
    unsigned short* vtb    = (unsigned short*)(ws + 42467328);  // 12,582,912 B
    unsigned short* ctx    = (unsigned short*)(ws + 55050240);  // 12,582,912 B  (total ~67.6 MB)

    k_cvt_bf16<<<6144, 256, 0, stream>>>(x, xb, 1572864);
    k_transpose_bf16<<<dim3(12, 36), 256, 0, stream>>>(w_qkv, wqkvt, 768, 2304);
    k_transpose_bf16<<<dim3(12, 12), 256, 0, stream>>>(w_proj, wprojt, 768, 768);
    k_gemm_qkv<<<dim3(64, 18), 256, 0, stream>>>(xb, wqkvt, b_qkv, qbuf, kbuf, vtb);
    k_attn<<<3072, 256, 0, stream>>>(qbuf, kbuf, vtb, mask, pb, attO, ctx);
    k_gemm_proj<<<dim3(64, 6), 256, 0, stream>>>(ctx, wprojt, b_proj, out);
}